// Round 4
// baseline (705.984 us; speedup 1.0000x reference)
//
#include <hip/hip_runtime.h>
#include <hip/hip_bf16.h>

// SpatialWindowSelfAttention — MI355X gfx950. ZERO-workspace design.
// Inputs f32: x[131072,256], h, w, wqkv_w[768,256], wqkv_b[768],
// wp_w[256,256], wp_b[256], bias_table[225,8]. OUTPUT f32 [131072,256]
// (reference output dtype is float32 — R2/R3 failed by writing bf16).
// K1: per-window fused QKV proj + window attention -> Y (f32) into d_out.
// K2: in-place output projection on d_out (block owns full rows).

typedef __bf16 bf16;
typedef bf16 bf16x4 __attribute__((ext_vector_type(4)));
typedef bf16 bf16x8 __attribute__((ext_vector_type(8)));
typedef float f32x4 __attribute__((ext_vector_type(4)));

#define MFMA16(a, b, c) __builtin_amdgcn_mfma_f32_16x16x32_bf16(a, b, c, 0, 0, 0)

__device__ __forceinline__ bf16x8 cvt8(const float* p) {  // 32B-aligned f32 -> bf16x8
  f32x4 lo = *(const f32x4*)p;
  f32x4 hi = *(const f32x4*)(p + 4);
  bf16x8 r;
#pragma unroll
  for (int j = 0; j < 4; j++) { r[j] = (bf16)lo[j]; r[j + 4] = (bf16)hi[j]; }
  return r;
}
__device__ __forceinline__ bf16x8 lds8(const bf16* p) {  // 8B-aligned LDS pair
  bf16x4 lo = *(const bf16x4*)p;
  bf16x4 hi = *(const bf16x4*)(p + 4);
  return __builtin_shufflevector(lo, hi, 0, 1, 2, 3, 4, 5, 6, 7);
}

// Per-wave LDS union (elements): Qs[64][36]@0, Ks[64][36]@2304, Vt[32][68]@4608,
// Pl[64][68]@0 (clobbers Qs/Ks AFTER their reads; Vt disjoint from all).
#define QS_OFF 0
#define KS_OFF 2304
#define VT_OFF 4608
#define PL_OFF 0
#define UNI_SZ 6784

__global__ __launch_bounds__(256) void fused_qkv_attn(
    const float* __restrict__ x, const float* __restrict__ wqkv_w,
    const float* __restrict__ wqkv_b, const float* __restrict__ bias_table,
    float* __restrict__ out) {
  __shared__ bf16 xs[64][72];        // x K-chunk: 64 tokens x 64 ch (+8 pad)
  __shared__ bf16 uni[4][UNI_SZ];    // per-wave scratch

  const int tid = threadIdx.x;
  const int wave = tid >> 6, lane = tid & 63;
  const int lr = lane & 15, quad = lane >> 4;
  const int win = blockIdx.x;                      // [0,2048)
  const int batch = win >> 10, wy = (win >> 5) & 31, wx = win & 31;
  const int base = batch * 65536 + wy * 2048 + wx * 8;  // token row base
  bf16* const U = &uni[wave][0];

  const f32x4 zero = {0.f, 0.f, 0.f, 0.f};
  const float scale = 0.17677669529663687f;  // 1/sqrt(32)

  for (int rep = 0; rep < 2; rep++) {
    const int h = wave * 2 + rep;
    const int cb[6] = {h * 32,       h * 32 + 16,        // Q cols
                       256 + h * 32, 256 + h * 32 + 16,  // K cols
                       512 + h * 32, 512 + h * 32 + 16}; // V cols

    // ---- QKV projection for head h: [64 tok] x [96 ch], K=256 ----
    f32x4 acc[4][6] = {};
    for (int kc = 0; kc < 4; kc++) {
      __syncthreads();  // prior xs reads done before overwrite
      {
        const int t = tid >> 2, c0 = (tid & 3) * 16;
        const float* xp = x + (size_t)(base + (t >> 3) * 256 + (t & 7)) * 256 + kc * 64 + c0;
        *(bf16x8*)&xs[t][c0] = cvt8(xp);
        *(bf16x8*)&xs[t][c0 + 8] = cvt8(xp + 8);
      }
      __syncthreads();
#pragma unroll
      for (int k2 = 0; k2 < 64; k2 += 32) {
        bf16x8 a[4], b[6];
#pragma unroll
        for (int mi = 0; mi < 4; mi++) a[mi] = lds8(&xs[mi * 16 + lr][k2 + quad * 8]);
#pragma unroll
        for (int nj = 0; nj < 6; nj++)
          b[nj] = cvt8(wqkv_w + (size_t)(cb[nj] + lr) * 256 + kc * 64 + k2 + quad * 8);
#pragma unroll
        for (int mi = 0; mi < 4; mi++)
#pragma unroll
          for (int nj = 0; nj < 6; nj++) acc[mi][nj] = MFMA16(a[mi], b[nj], acc[mi][nj]);
      }
    }

    // ---- epilogue: Q,K -> LDS [token][d]; V -> LDS transposed [d][token] ----
#pragma unroll
    for (int nj = 0; nj < 6; nj++) {
      const float bv = wqkv_b[cb[nj] + lr];
#pragma unroll
      for (int mi = 0; mi < 4; mi++)
#pragma unroll
        for (int r = 0; r < 4; r++) {
          const int tok = mi * 16 + quad * 4 + r;  // C/D row
          const float v = acc[mi][nj][r] + bv;
          if (nj < 2)      U[QS_OFF + tok * 36 + nj * 16 + lr] = (bf16)v;
          else if (nj < 4) U[KS_OFF + tok * 36 + (nj - 2) * 16 + lr] = (bf16)v;
          else             U[VT_OFF + ((nj - 4) * 16 + lr) * 68 + tok] = (bf16)v;
        }
    }

    // ---- S = Q K^T * scale + bias ----
    bf16x8 qf[4], kf[4];
#pragma unroll
    for (int i = 0; i < 4; i++) {
      qf[i] = lds8(&U[QS_OFF + (i * 16 + lr) * 36 + quad * 8]);  // A: m=lr, k=d
      kf[i] = lds8(&U[KS_OFF + (i * 16 + lr) * 36 + quad * 8]);  // B: n=lr, k=d
    }
    f32x4 s[4][4];
#pragma unroll
    for (int mi = 0; mi < 4; mi++)
#pragma unroll
      for (int nj = 0; nj < 4; nj++) s[mi][nj] = MFMA16(qf[mi], kf[nj], zero);

#pragma unroll
    for (int mi = 0; mi < 4; mi++)
#pragma unroll
      for (int nj = 0; nj < 4; nj++)
#pragma unroll
        for (int r = 0; r < 4; r++) {
          const int qt = mi * 16 + quad * 4 + r;
          const int kt = nj * 16 + lr;
          const int idx = ((qt >> 3) - (kt >> 3) + 7) * 15 + ((qt & 7) - (kt & 7) + 7);
          s[mi][nj][r] = s[mi][nj][r] * scale + bias_table[idx * 8 + h];
        }

    // ---- row softmax; P -> LDS (clobbers Qs/Ks region: already consumed) ----
#pragma unroll
    for (int mi = 0; mi < 4; mi++)
#pragma unroll
      for (int r = 0; r < 4; r++) {
        float mx = -1e30f;
#pragma unroll
        for (int nj = 0; nj < 4; nj++) mx = fmaxf(mx, s[mi][nj][r]);
#pragma unroll
        for (int off = 1; off < 16; off <<= 1) mx = fmaxf(mx, __shfl_xor(mx, off, 64));
        float sum = 0.f;
#pragma unroll
        for (int nj = 0; nj < 4; nj++) {
          const float e = __expf(s[mi][nj][r] - mx);
          s[mi][nj][r] = e;
          sum += e;
        }
#pragma unroll
        for (int off = 1; off < 16; off <<= 1) sum += __shfl_xor(sum, off, 64);
        const float inv = 1.0f / sum;
#pragma unroll
        for (int nj = 0; nj < 4; nj++)
          U[PL_OFF + (mi * 16 + quad * 4 + r) * 68 + nj * 16 + lr] = (bf16)(s[mi][nj][r] * inv);
      }

    // ---- O = P @ V : M=64 q, N=32 d, K=64 tok ----
    f32x4 o[4][2] = {};
#pragma unroll
    for (int kq = 0; kq < 2; kq++) {
      bf16x8 pa[4], vb[2];
#pragma unroll
      for (int mi = 0; mi < 4; mi++)
        pa[mi] = lds8(&U[PL_OFF + (mi * 16 + lr) * 68 + kq * 32 + quad * 8]);
#pragma unroll
      for (int ni = 0; ni < 2; ni++)
        vb[ni] = lds8(&U[VT_OFF + (ni * 16 + lr) * 68 + kq * 32 + quad * 8]);
#pragma unroll
      for (int mi = 0; mi < 4; mi++)
#pragma unroll
        for (int ni = 0; ni < 2; ni++) o[mi][ni] = MFMA16(pa[mi], vb[ni], o[mi][ni]);
    }

    // ---- store Y slice (f32) into d_out ----
#pragma unroll
    for (int mi = 0; mi < 4; mi++)
#pragma unroll
      for (int ni = 0; ni < 2; ni++)
#pragma unroll
        for (int r = 0; r < 4; r++) {
          const int t = mi * 16 + quad * 4 + r;
          const size_t row = (size_t)(base + (t >> 3) * 256 + (t & 7));
          out[row * 256 + h * 32 + ni * 16 + lr] = o[mi][ni][r];
        }
  }
}

// In-place projection: io[rows] <- io[rows] @ wp^T + b (f32 in/out).
// Block owns 128 rows, computes ALL 256 cols (K = full row). __syncthreads
// separates all reads from all writes; no cross-block row sharing.
__global__ __launch_bounds__(256) void proj_inplace(
    float* io, const float* __restrict__ W, const float* __restrict__ bias) {
  const int tid = threadIdx.x;
  const int wave = tid >> 6, lane = tid & 63;
  const int lr = lane & 15, quad = lane >> 4;
  const int row0 = blockIdx.x * 128 + (wave >> 1) * 64;
  const int col0 = (wave & 1) * 128;

  f32x4 acc[4][8] = {};
#pragma unroll
  for (int kk = 0; kk < 256; kk += 32) {
    bf16x8 a[4], b[8];
#pragma unroll
    for (int mi = 0; mi < 4; mi++)
      a[mi] = cvt8(io + (size_t)(row0 + mi * 16 + lr) * 256 + kk + quad * 8);
#pragma unroll
    for (int nj = 0; nj < 8; nj++)
      b[nj] = cvt8(W + (size_t)(col0 + nj * 16 + lr) * 256 + kk + quad * 8);
#pragma unroll
    for (int mi = 0; mi < 4; mi++)
#pragma unroll
      for (int nj = 0; nj < 8; nj++) acc[mi][nj] = MFMA16(a[mi], b[nj], acc[mi][nj]);
  }
  __syncthreads();  // ALL waves' reads of this block's rows complete before any write
#pragma unroll
  for (int mi = 0; mi < 4; mi++)
#pragma unroll
    for (int nj = 0; nj < 8; nj++) {
      const int col = col0 + nj * 16 + lr;
      const float bv = bias[col];
#pragma unroll
      for (int r = 0; r < 4; r++) {
        const int row = row0 + mi * 16 + quad * 4 + r;
        io[(size_t)row * 256 + col] = acc[mi][nj][r] + bv;
      }
    }
}

extern "C" void kernel_launch(void* const* d_in, const int* in_sizes, int n_in,
                              void* d_out, int out_size, void* d_ws, size_t ws_size,
                              hipStream_t stream) {
  const float* x = (const float*)d_in[0];
  // d_in[1]=h, d_in[2]=w (fixed 256)
  const float* wqkv_w = (const float*)d_in[3];
  const float* wqkv_b = (const float*)d_in[4];
  const float* wp_w = (const float*)d_in[5];
  const float* wp_b = (const float*)d_in[6];
  const float* bias_table = (const float*)d_in[7];
  float* out = (float*)d_out;

  fused_qkv_attn<<<2048, 256, 0, stream>>>(x, wqkv_w, wqkv_b, bias_table, out);
  proj_inplace<<<1024, 256, 0, stream>>>(out, wp_w, wp_b);
}